// Round 6
// baseline (17.153 us; speedup 1.0000x reference)
//
#include <hip/hip_runtime.h>
#include <math.h>

// Shapes fixed by the problem: B=2, S=512, E=256, H=8, D=32, 33 relation buckets.
// Algebra: scores=(qk_diag[i]+q_i.r_ij)*scale, qk_diag j-independent -> cancels
// EXACTLY in softmax_j -> key/W_K dead; alpha depends on j only via the 33
// relation buckets -> exact 33-bucket softmax reassociation:
//   w_r = cnt[r]*exp(s_r-m)/sum ;  out = v + sum_r w_r * rel_emb[r]
namespace {
constexpr int E_  = 256;
constexpr int D_  = 32;
constexpr int S_  = 512;
constexpr int NR_ = 33;
constexpr int RC_ = 32;                 // rows per block
constexpr int ROWS_ = 1024;
constexpr int H_  = 8;
}

using f32x4 = __attribute__((ext_vector_type(4))) float;
using s16x8 = __attribute__((ext_vector_type(8))) short;

// fp32 -> bf16 round-to-nearest-even
__device__ inline unsigned pk_bf16(float a, float b) {
    unsigned ua = __float_as_uint(a); ua += 0x7FFFu + ((ua >> 16) & 1u);
    unsigned ub = __float_as_uint(b); ub += 0x7FFFu + ((ub >> 16) & 1u);
    return (ua >> 16) | (ub & 0xFFFF0000u);
}
__device__ inline unsigned short bf16_1(float a) {
    unsigned ua = __float_as_uint(a); ua += 0x7FFFu + ((ua >> 16) & 1u);
    return (unsigned short)(ua >> 16);
}
// two float4 (8 consecutive fp32) -> one bf16 MFMA fragment operand
__device__ inline s16x8 cvt8(const float4 a, const float4 b) {
    union { unsigned u[4]; s16x8 v; } r;
    r.u[0] = pk_bf16(a.x, a.y); r.u[1] = pk_bf16(a.z, a.w);
    r.u[2] = pk_bf16(b.x, b.y); r.u[3] = pk_bf16(b.z, b.w);
    return r.v;
}

// LDS-only barrier (prefetched global loads stay in flight; rule #18 fence).
__device__ inline void bar_lgkm() {
    asm volatile("s_waitcnt lgkmcnt(0)" ::: "memory");
    __builtin_amdgcn_s_barrier();
    __builtin_amdgcn_sched_barrier(0);
}

// ---------------------------------------------------------------------------
// One fused kernel, 3 barriers. Block (chunk,h): rows [chunk*32,+32), head h.
// GEMM operands load DIRECTLY from global into MFMA fragments (no LDS tiles):
// lane l of wave w needs q[r0+mi+ (l&15)][ks*32+(l>>4)*8 ..+8] = 2 float4.
// grid=(32,8)=256 blocks (1/CU; all 8 head-blocks of a chunk share an XCD).
// ---------------------------------------------------------------------------
__global__ __launch_bounds__(256) void fused_kernel(
    const float* __restrict__ q_in, const float* __restrict__ v_in,
    const float* __restrict__ WQ,  const float* __restrict__ WV,
    const int*   __restrict__ relations,   // [B,S,S] int32
    const float* __restrict__ rel_emb,     // [33, E]
    float* __restrict__ out)               // [B,S,E]
{
    __shared__ __align__(16) float v_s[RC_][36];              // 4.6 KB fp32 v
    __shared__ __align__(16) unsigned short qbf_s[RC_ * 32];  // 2 KB bf16 q [row][k]
    __shared__ __align__(16) float emb_s[NR_ * D_];           // 4.2 KB fp32 emb slice
    __shared__ __align__(16) unsigned short ebf_s[48 * 32];   // 3 KB bf16 emb (pad rows unread)
    __shared__ float qr_s[RC_][48];                           // 6 KB scores
    __shared__ int   cnt_s[RC_ * NR_];                        // 4.2 KB

    const int t  = threadIdx.x;
    const int r0 = blockIdx.x * RC_;
    const int h  = blockIdx.y;
    const int c0 = h * D_;

    const int l  = t & 63;
    const int w  = t >> 6;
    const int mi = (w >> 1) * 16;          // row quadrant
    const int ni = (w & 1) * 16;           // col quadrant
    const int lr = l & 15;
    const int lg = l >> 4;                 // k-group (8 fp32 each)

    // ---- issue relation loads immediately (16 int4/thread)
    const int hrow = t >> 3, hl = t & 7;
    int4 rel[16];
    {
        const int* relrow = relations + (size_t)(r0 + hrow) * S_;
        #pragma unroll
        for (int i = 0; i < 16; ++i)
            rel[i] = *reinterpret_cast<const int4*>(&relrow[hl * 4 + i * 32]);
    }

    // ---- stage rel_emb head-slice (fp32 + bf16 copies), zero histogram
    for (int g = t; g < NR_ * D_ / 4; g += 256) {       // 264 float4
        const int r = g >> 3, d4 = (g & 7) * 4;
        const float4 ev = *reinterpret_cast<const float4*>(
            &rel_emb[(size_t)r * E_ + c0 + d4]);
        *reinterpret_cast<float4*>(&emb_s[r * D_ + d4]) = ev;
        *reinterpret_cast<uint2*>(&ebf_s[r * 32 + d4]) =
            make_uint2(pk_bf16(ev.x, ev.y), pk_bf16(ev.z, ev.w));
    }
    for (int i = t; i < RC_ * NR_; i += 256) cnt_s[i] = 0;
    bar_lgkm();                                         // B1: cnt zeroed

    // ---- projection GEMMs straight from global (no LDS staging)
    const float* qrow = q_in + (size_t)(r0 + mi + lr) * E_ + lg * 8;
    const float* vrow = v_in + (size_t)(r0 + mi + lr) * E_ + lg * 8;
    const float* wqr  = WQ   + (size_t)(c0 + ni + lr) * E_ + lg * 8;
    const float* wvr  = WV   + (size_t)(c0 + ni + lr) * E_ + lg * 8;

    f32x4 accq = {}, accv = {};
    #pragma unroll
    for (int ks = 0; ks < 8; ++ks) {
        const float4* q4 = reinterpret_cast<const float4*>(qrow + ks * 32);
        const float4* v4 = reinterpret_cast<const float4*>(vrow + ks * 32);
        const float4* a4 = reinterpret_cast<const float4*>(wqr  + ks * 32);
        const float4* b4 = reinterpret_cast<const float4*>(wvr  + ks * 32);
        const s16x8 aq = cvt8(q4[0], q4[1]);
        const s16x8 av = cvt8(v4[0], v4[1]);
        const s16x8 bq = cvt8(a4[0], a4[1]);
        const s16x8 bv = cvt8(b4[0], b4[1]);
        accq = __builtin_amdgcn_mfma_f32_16x16x32_bf16(aq, bq, accq, 0, 0, 0);
        accv = __builtin_amdgcn_mfma_f32_16x16x32_bf16(av, bv, accv, 0, 0, 0);
    }

    // ---- histogram (rel long landed; drains into LDS before B2)
    #pragma unroll
    for (int i = 0; i < 16; ++i) {
        const int4 rv = rel[i];
        atomicAdd(&cnt_s[hrow * NR_ + rv.x], 1);
        atomicAdd(&cnt_s[hrow * NR_ + rv.y], 1);
        atomicAdd(&cnt_s[hrow * NR_ + rv.z], 1);
        atomicAdd(&cnt_s[hrow * NR_ + rv.w], 1);
    }

    // ---- write projections: v fp32, q bf16 (C: col=lane&15, row=(lane>>4)*4+j)
    #pragma unroll
    for (int j = 0; j < 4; ++j) {
        const int row = mi + lg * 4 + j;
        const int col = ni + lr;
        v_s[row][col] = accv[j];
        qbf_s[row * 32 + col] = bf16_1(accq[j]);
    }
    bar_lgkm();                                         // B2

    // ---- qr[row][r] = q_row . emb_r  via MFMA (32x48, K=32)
    {
        const int kq = lg * 8;
        const int Hh = w >> 1;
        const int G  = w & 1;
        const s16x8 afr = *reinterpret_cast<const s16x8*>(&qbf_s[(Hh * 16 + lr) * 32 + kq]);
        const s16x8 bfr = *reinterpret_cast<const s16x8*>(&ebf_s[(G  * 16 + lr) * 32 + kq]);
        f32x4 r1 = {};
        r1 = __builtin_amdgcn_mfma_f32_16x16x32_bf16(afr, bfr, r1, 0, 0, 0);
        #pragma unroll
        for (int j = 0; j < 4; ++j)
            qr_s[Hh * 16 + lg * 4 + j][G * 16 + lr] = r1[j];
        if ((w & 1) == 0) {                  // waves 0,2 also do buckets 32-47
            const s16x8 bf2 = *reinterpret_cast<const s16x8*>(&ebf_s[(32 + lr) * 32 + kq]);
            f32x4 r2 = {};
            r2 = __builtin_amdgcn_mfma_f32_16x16x32_bf16(afr, bf2, r2, 0, 0, 0);
            #pragma unroll
            for (int j = 0; j < 4; ++j)
                qr_s[Hh * 16 + lg * 4 + j][32 + lr] = r2[j];
        }
    }
    bar_lgkm();                                         // B3

    // ---- bucket softmax (8 lanes/row) + output, weights via shfl (no barrier)
    const int erow = t >> 3, el = t & 7;
    float e[5];
    float inv;
    {
        constexpr float scale = 0.17677669529663687f;   // 1/sqrt(32)
        float z[5], m = -1e30f;
        #pragma unroll
        for (int u = 0; u < 5; ++u) {
            const int r = el + 8 * u;
            z[u] = (r < NR_) ? qr_s[erow][r] * scale : -1e30f;
            m = fmaxf(m, z[u]);
        }
        m = fmaxf(m, __shfl_xor(m, 1));
        m = fmaxf(m, __shfl_xor(m, 2));
        m = fmaxf(m, __shfl_xor(m, 4));
        float sum = 0.f;
        #pragma unroll
        for (int u = 0; u < 5; ++u) {
            const int r = el + 8 * u;
            e[u] = (r < NR_) ? (float)cnt_s[erow * NR_ + r] * __expf(z[u] - m) : 0.f;
            sum += e[u];
        }
        sum += __shfl_xor(sum, 1);
        sum += __shfl_xor(sum, 2);
        sum += __shfl_xor(sum, 4);
        inv = 1.0f / sum;
    }
    {
        const int d0 = el * 4;
        f32x4 acc = *reinterpret_cast<const f32x4*>(&v_s[erow][d0]);
        const int base = l & 56;                        // 8-lane group base
        #pragma unroll
        for (int r = 0; r < NR_; ++r) {
            const float wv = __shfl(e[r >> 3], base | (r & 7)) * inv;
            const f32x4 ev = *reinterpret_cast<const f32x4*>(&emb_s[r * D_ + d0]);
            acc[0] += wv * ev[0]; acc[1] += wv * ev[1];
            acc[2] += wv * ev[2]; acc[3] += wv * ev[3];
        }
        *reinterpret_cast<f32x4*>(&out[(size_t)(r0 + erow) * E_ + c0 + d0]) = acc;
    }
}

extern "C" void kernel_launch(void* const* d_in, const int* in_sizes, int n_in,
                              void* d_out, int out_size, void* d_ws, size_t ws_size,
                              hipStream_t stream) {
    const float* query     = (const float*)d_in[0];
    const float* value     = (const float*)d_in[2];
    const int*   relations = (const int*)  d_in[3];
    const float* W_Q       = (const float*)d_in[4];
    const float* W_V       = (const float*)d_in[6];
    const float* rel_emb   = (const float*)d_in[7];
    float* out = (float*)d_out;

    dim3 grid(ROWS_ / RC_, H_);            // (32, 8) = 256 blocks, one per CU
    fused_kernel<<<grid, 256, 0, stream>>>(query, value, W_Q, W_V,
                                           relations, rel_emb, out);
}

// Round 8
// 13.054 us; speedup vs baseline: 1.3140x; 1.3140x over previous
//
#include <hip/hip_runtime.h>
#include <math.h>

// Shapes fixed by the problem: B=2, S=512, E=256, H=8, D=32, 33 relation buckets.
// Algebra: scores=(qk_diag[i]+q_i.r_ij)*scale, qk_diag j-independent -> cancels
// EXACTLY in softmax_j -> key/W_K dead; alpha depends on j only via the 33
// relation buckets -> exact 33-bucket softmax reassociation:
//   w_r = cnt[r]*exp(s_r-m)/sum ;  out = v + sum_r w_r * rel_emb[r]
namespace {
constexpr int E_  = 256;
constexpr int D_  = 32;
constexpr int S_  = 512;
constexpr int NR_ = 33;
constexpr int RC_ = 16;                 // seq rows per block
constexpr int ROWS_ = 1024;
constexpr int H_  = 8;
}

using f32x4 = __attribute__((ext_vector_type(4))) float;
using s16x8 = __attribute__((ext_vector_type(8))) short;

// fp32 -> bf16 round-to-nearest-even
__device__ inline unsigned pk_bf16(float a, float b) {
    unsigned ua = __float_as_uint(a); ua += 0x7FFFu + ((ua >> 16) & 1u);
    unsigned ub = __float_as_uint(b); ub += 0x7FFFu + ((ub >> 16) & 1u);
    return (ua >> 16) | (ub & 0xFFFF0000u);
}
__device__ inline unsigned short bf16_1(float a) {
    unsigned ua = __float_as_uint(a); ua += 0x7FFFu + ((ua >> 16) & 1u);
    return (unsigned short)(ua >> 16);
}

// XOR-swizzled byte offset within a [16 rows][512 B] bf16 tile (full K=256):
// fragment reads spread 8 banks per 16-lane group -> 2 lanes/bank = free (m136).
__device__ inline int swz(int row, int kbyte) {
    return row * 512 + (kbyte ^ ((row & 7) << 4));
}

// LDS-only barrier (global loads stay in flight; rule #18 fence after lgkm).
__device__ inline void bar_lgkm() {
    asm volatile("s_waitcnt lgkmcnt(0)" ::: "memory");
    __builtin_amdgcn_s_barrier();
    __builtin_amdgcn_sched_barrier(0);
}

// ---------------------------------------------------------------------------
// One fused kernel, 3 barriers. Block (chunk,h): rows [chunk*16,+16), head h.
// Six 16-row full-K tiles staged once: q, v, WQ rows c0+0..15, WQ c0+16..31,
// WV c0+0..15, WV c0+16..31  (R7 bug: W slices need 32 rows, not 16).
// Wave w: matrix (w>>1 ? v : q), col-half (w&1) vs its own B sub-tile.
// grid=(64,8)=512 blocks -> 2 blocks/CU for latency hiding.
// ---------------------------------------------------------------------------
__global__ __launch_bounds__(256, 2) void fused_kernel(
    const float* __restrict__ q_in, const float* __restrict__ v_in,
    const float* __restrict__ WQ,  const float* __restrict__ WV,
    const int*   __restrict__ relations,   // [B,S,S] int32
    const float* __restrict__ rel_emb,     // [33, E]
    float* __restrict__ out)               // [B,S,E]
{
    __shared__ __align__(16) char  tiles[6][RC_ * 512];       // 48 KB
    __shared__ __align__(16) float v_s[RC_][36];              // 2.3 KB fp32 v
    __shared__ __align__(16) unsigned short qbf_s[RC_ * 32];  // 1 KB bf16 q
    __shared__ __align__(16) float emb_s[NR_ * D_];           // 4.2 KB fp32 emb slice
    __shared__ __align__(16) unsigned short ebf_s[48 * 32];   // 3 KB bf16 emb (rows 33-47 zero)
    __shared__ float qr_s[RC_][49];                           // 3.1 KB scores
    __shared__ int   cnt_s[RC_ * NR_];                        // 2.1 KB   total ~65.0 KB

    const int t  = threadIdx.x;
    const int r0 = blockIdx.x * RC_;
    const int h  = blockIdx.y;
    const int c0 = h * D_;

    const int l  = t & 63;
    const int w  = t >> 6;
    const int lr = l & 15;
    const int lg = l >> 4;                 // k-group (8 fp32)

    // ---- issue ALL global loads up front -----------------------------------
    const int hrow = t >> 4, hl = t & 15;
    int4 rel[8];
    {
        const int* relrow = relations + (size_t)(r0 + hrow) * S_;
        #pragma unroll
        for (int i = 0; i < 8; ++i)
            rel[i] = *reinterpret_cast<const int4*>(&relrow[hl * 4 + i * 64]);
    }
    // staging: 6 tiles x 16 rows x 64 float4 = 24 tasks/thread; per jj a wave
    // loads one contiguous 1 KB row (fully coalesced).
    float4 stg[24];
    #pragma unroll
    for (int jj = 0; jj < 24; ++jj) {
        const int tile = jj >> 2;
        const int row  = (jj & 3) * 4 + (t >> 6);
        const int col4 = t & 63;
        const float* src = (tile == 0) ? q_in : (tile == 1) ? v_in
                         : (tile < 4)  ? WQ   : WV;
        const int rb = (tile < 2) ? r0 : c0 + ((tile & 1) ? 16 : 0);
        stg[jj] = *reinterpret_cast<const float4*>(
            &src[(size_t)(rb + row) * E_ + col4 * 4]);
    }
    // rel_emb head-slice: 264 float4
    float4 ev0{}, ev1{};
    ev0 = *reinterpret_cast<const float4*>(
        &rel_emb[(size_t)(t >> 3) * E_ + c0 + (t & 7) * 4]);
    if (t < 8) ev1 = *reinterpret_cast<const float4*>(
        &rel_emb[(size_t)32 * E_ + c0 + t * 4]);

    // ---- LDS init ----------------------------------------------------------
    {
        const int r = t >> 3, d4 = (t & 7) * 4;
        *reinterpret_cast<float4*>(&emb_s[r * D_ + d4]) = ev0;
        *reinterpret_cast<uint2*>(&ebf_s[r * 32 + d4]) =
            make_uint2(pk_bf16(ev0.x, ev0.y), pk_bf16(ev0.z, ev0.w));
        if (t < 8) {
            *reinterpret_cast<float4*>(&emb_s[32 * D_ + t * 4]) = ev1;
            *reinterpret_cast<uint2*>(&ebf_s[32 * 32 + t * 4]) =
                make_uint2(pk_bf16(ev1.x, ev1.y), pk_bf16(ev1.z, ev1.w));
        }
        if (t < 240) reinterpret_cast<unsigned*>(ebf_s + 33 * 32)[t] = 0;
    }
    for (int i = t; i < RC_ * NR_; i += 256) cnt_s[i] = 0;
    #pragma unroll
    for (int jj = 0; jj < 24; ++jj) {
        const int tile = jj >> 2;
        const int row  = (jj & 3) * 4 + (t >> 6);
        const int col4 = t & 63;
        const float4 p = stg[jj];
        *reinterpret_cast<uint2*>(tiles[tile] + swz(row, col4 * 8)) =
            make_uint2(pk_bf16(p.x, p.y), pk_bf16(p.z, p.w));
    }
    bar_lgkm();                                         // B1: everything staged

    // ---- projection MFMAs: wave w -> matrix (w>>1), col-half (w&1) ---------
    const int mat = w >> 1;                // 0 = q/WQ, 1 = v/WV
    const int ch  = w & 1;                 // col half
    const char* At = tiles[mat];
    const char* Bt = tiles[2 + mat * 2 + ch];
    f32x4 acc = {};
    #pragma unroll
    for (int ks = 0; ks < 8; ++ks) {
        const int kb = ks * 64 + lg * 16;
        const s16x8 af = *reinterpret_cast<const s16x8*>(At + swz(lr, kb));
        const s16x8 bf = *reinterpret_cast<const s16x8*>(Bt + swz(lr, kb));
        acc = __builtin_amdgcn_mfma_f32_16x16x32_bf16(af, bf, acc, 0, 0, 0);
    }

    // ---- histogram (rel loads long landed) ---------------------------------
    #pragma unroll
    for (int i = 0; i < 8; ++i) {
        const int4 rv = rel[i];
        atomicAdd(&cnt_s[hrow * NR_ + rv.x], 1);
        atomicAdd(&cnt_s[hrow * NR_ + rv.y], 1);
        atomicAdd(&cnt_s[hrow * NR_ + rv.z], 1);
        atomicAdd(&cnt_s[hrow * NR_ + rv.w], 1);
    }

    // ---- write projections (C: col=lane&15, row=(lane>>4)*4+j) -------------
    #pragma unroll
    for (int j = 0; j < 4; ++j) {
        const int row = lg * 4 + j;
        const int col = ch * 16 + lr;
        if (mat == 0) qbf_s[row * 32 + col] = bf16_1(acc[j]);
        else          v_s[row][col] = acc[j];
    }
    bar_lgkm();                                         // B2

    // ---- qr[row][r] = q_row . emb_r via MFMA (16x48, K=32) -----------------
    if (w < 3) {
        const int G = w;                   // bucket group
        const s16x8 afr = *reinterpret_cast<const s16x8*>(&qbf_s[lr * 32 + lg * 8]);
        const s16x8 bfr = *reinterpret_cast<const s16x8*>(&ebf_s[(G * 16 + lr) * 32 + lg * 8]);
        f32x4 r1 = {};
        r1 = __builtin_amdgcn_mfma_f32_16x16x32_bf16(afr, bfr, r1, 0, 0, 0);
        #pragma unroll
        for (int j = 0; j < 4; ++j)
            qr_s[lg * 4 + j][G * 16 + lr] = r1[j];
    }
    bar_lgkm();                                         // B3

    // ---- bucket softmax (16 lanes/row) + output, weights via shfl ----------
    const int erow = hrow, el = hl;
    float e[3];
    float inv;
    {
        constexpr float scale = 0.17677669529663687f;   // 1/sqrt(32)
        float z[3], m = -1e30f;
        #pragma unroll
        for (int u = 0; u < 3; ++u) {
            const int r = el + 16 * u;
            z[u] = (r < NR_) ? qr_s[erow][r] * scale : -1e30f;
            m = fmaxf(m, z[u]);
        }
        m = fmaxf(m, __shfl_xor(m, 1));
        m = fmaxf(m, __shfl_xor(m, 2));
        m = fmaxf(m, __shfl_xor(m, 4));
        m = fmaxf(m, __shfl_xor(m, 8));
        float sum = 0.f;
        #pragma unroll
        for (int u = 0; u < 3; ++u) {
            const int r = el + 16 * u;
            e[u] = (r < NR_) ? (float)cnt_s[erow * NR_ + r] * __expf(z[u] - m) : 0.f;
            sum += e[u];
        }
        sum += __shfl_xor(sum, 1);
        sum += __shfl_xor(sum, 2);
        sum += __shfl_xor(sum, 4);
        sum += __shfl_xor(sum, 8);
        inv = 1.0f / sum;
    }
    {
        const int d0 = el * 2;                          // float2 per lane
        float2 acc2 = *reinterpret_cast<const float2*>(&v_s[erow][d0]);
        const int base = l & 48;                        // 16-lane group base
        #pragma unroll
        for (int r = 0; r < NR_; ++r) {
            const float wv = __shfl(e[r >> 4], base | (r & 15)) * inv;
            const float2 ev = *reinterpret_cast<const float2*>(&emb_s[r * D_ + d0]);
            acc2.x += wv * ev.x;
            acc2.y += wv * ev.y;
        }
        *reinterpret_cast<float2*>(&out[(size_t)(r0 + erow) * E_ + c0 + d0]) = acc2;
    }
}

extern "C" void kernel_launch(void* const* d_in, const int* in_sizes, int n_in,
                              void* d_out, int out_size, void* d_ws, size_t ws_size,
                              hipStream_t stream) {
    const float* query     = (const float*)d_in[0];
    const float* value     = (const float*)d_in[2];
    const int*   relations = (const int*)  d_in[3];
    const float* W_Q       = (const float*)d_in[4];
    const float* W_V       = (const float*)d_in[6];
    const float* rel_emb   = (const float*)d_in[7];
    float* out = (float*)d_out;

    dim3 grid(ROWS_ / RC_, H_);            // (64, 8) = 512 blocks, 2 per CU
    fused_kernel<<<grid, 256, 0, stream>>>(query, value, W_Q, W_V,
                                           relations, rel_emb, out);
}

// Round 9
// 12.458 us; speedup vs baseline: 1.3769x; 1.0479x over previous
//
#include <hip/hip_runtime.h>
#include <math.h>

// Shapes fixed by the problem: B=2, S=512, E=256, H=8, D=32, 33 relation buckets.
// Algebra: scores=(qk_diag[i]+q_i.r_ij)*scale, qk_diag j-independent -> cancels
// EXACTLY in softmax_j -> key/W_K dead; alpha depends on j only via the 33
// relation buckets -> exact 33-bucket softmax reassociation:
//   w_r = cnt[r]*exp(s_r-m)/sum ;  out = v + sum_r w_r * rel_emb[r]
namespace {
constexpr int E_  = 256;
constexpr int D_  = 32;
constexpr int S_  = 512;
constexpr int NR_ = 33;
constexpr int RC_ = 32;                 // rows per block (R5 geometry)
constexpr int ROWS_ = 1024;
constexpr int H_  = 8;
}

using f32x4 = __attribute__((ext_vector_type(4))) float;
using s16x8 = __attribute__((ext_vector_type(8))) short;

// fp32 -> bf16 round-to-nearest-even
__device__ inline unsigned pk_bf16(float a, float b) {
    unsigned ua = __float_as_uint(a); ua += 0x7FFFu + ((ua >> 16) & 1u);
    unsigned ub = __float_as_uint(b); ub += 0x7FFFu + ((ub >> 16) & 1u);
    return (ua >> 16) | (ub & 0xFFFF0000u);
}
__device__ inline unsigned short bf16_1(float a) {
    unsigned ua = __float_as_uint(a); ua += 0x7FFFu + ((ua >> 16) & 1u);
    return (unsigned short)(ua >> 16);
}

// XOR-swizzled byte offset within a [32 rows][128 B] bf16 k-tile (R5-proven).
__device__ inline int swz(int row, int kbyte) {
    return row * 128 + (kbyte ^ ((row & 7) << 4));
}

// LDS-only barrier (prefetched global loads stay in flight; rule #18 fence).
__device__ inline void bar_lgkm() {
    asm volatile("s_waitcnt lgkmcnt(0)" ::: "memory");
    __builtin_amdgcn_s_barrier();
    __builtin_amdgcn_sched_barrier(0);
}

// ---------------------------------------------------------------------------
// One fused kernel, 6 barriers. Block (chunk,h): rows [chunk*32,+32), head h.
// K=256 in 4 k-tiles of 64, LDS double-buffered: per k-tile a single barrier
// {write tile kt+1 -> other buf ; mfma tile kt ; bar}. 2-deep global prefetch.
// grid=(32,8)=256 blocks (1/CU).
// ---------------------------------------------------------------------------
__global__ __launch_bounds__(256) void fused_kernel(
    const float* __restrict__ q_in, const float* __restrict__ v_in,
    const float* __restrict__ WQ,  const float* __restrict__ WV,
    const int*   __restrict__ relations,   // [B,S,S] int32
    const float* __restrict__ rel_emb,     // [33, E]
    float* __restrict__ out)               // [B,S,E]
{
    __shared__ __align__(16) char  tiles[2][4][RC_ * 128];    // 32 KB dbuf q|v|WQ|WV
    __shared__ __align__(16) float v_s[RC_][36];              // 4.6 KB fp32 v
    __shared__ __align__(16) unsigned short qbf_s[RC_ * 32];  // 2 KB bf16 q [row][k]
    __shared__ __align__(16) float emb_s[NR_ * D_];           // 4.2 KB fp32 emb slice
    __shared__ __align__(16) unsigned short ebf_s[48 * 32];   // 3 KB bf16 emb (rows 33-47 zero)
    __shared__ float qr_s[RC_][52];                           // 6.6 KB scores
    __shared__ int   cnt_s[RC_ * NR_];                        // 4.2 KB   total ~56.6 KB

    const int t  = threadIdx.x;
    const int r0 = blockIdx.x * RC_;
    const int h  = blockIdx.y;
    const int c0 = h * D_;

    const int l  = t & 63;
    const int w  = t >> 6;
    const int mi = (w >> 1) * 16;          // row quadrant
    const int ni = (w & 1) * 16;           // col quadrant
    const int lr = l & 15;
    const int lk = (l >> 4) * 16;          // byte offset of 8-bf16 k-group

    float4 pre[2][8];                      // 2 k-tiles in flight (register slots)
    auto issue = [&](int kt, int slot) {
        #pragma unroll
        for (int j = 0; j < 8; ++j) {
            const int tau = j >> 1;                  // 0=q 1=v 2=WQ 3=WV
            const int idx = t + 256 * (j & 1);
            const int row = idx >> 4;
            const int cf  = (idx & 15) * 4;
            const float* src = (tau == 0) ? q_in : (tau == 1) ? v_in
                             : (tau == 2) ? WQ   : WV;
            const int rb = (tau < 2) ? r0 : c0;
            pre[slot][j] = *reinterpret_cast<const float4*>(
                &src[(size_t)(rb + row) * E_ + kt * 64 + cf]);
        }
    };
    auto wtiles = [&](int slot, int buf) {
        #pragma unroll
        for (int j = 0; j < 8; ++j) {
            const int tau = j >> 1;
            const int idx = t + 256 * (j & 1);
            const int row = idx >> 4;
            const int cb  = (idx & 15) * 8;
            const float4 p = pre[slot][j];
            *reinterpret_cast<uint2*>(tiles[buf][tau] + swz(row, cb)) =
                make_uint2(pk_bf16(p.x, p.y), pk_bf16(p.z, p.w));
        }
    };

    f32x4 accq = {}, accv = {};
    auto mfma_tile = [&](int buf) {
        #pragma unroll
        for (int s = 0; s < 2; ++s) {
            const int kb = s * 64 + lk;
            const s16x8 aq = *reinterpret_cast<const s16x8*>(tiles[buf][0] + swz(mi + lr, kb));
            const s16x8 av = *reinterpret_cast<const s16x8*>(tiles[buf][1] + swz(mi + lr, kb));
            const s16x8 bq = *reinterpret_cast<const s16x8*>(tiles[buf][2] + swz(ni + lr, kb));
            const s16x8 bv = *reinterpret_cast<const s16x8*>(tiles[buf][3] + swz(ni + lr, kb));
            accq = __builtin_amdgcn_mfma_f32_16x16x32_bf16(aq, bq, accq, 0, 0, 0);
            accv = __builtin_amdgcn_mfma_f32_16x16x32_bf16(av, bv, accv, 0, 0, 0);
        }
    };

    // ---- entry: issue tiles 0,1; load relations; stage emb; zero cnt -------
    issue(0, 0);
    issue(1, 1);
    const int hrow = t >> 3, hl = t & 7;
    int4 rel[16];
    {
        const int* relrow = relations + (size_t)(r0 + hrow) * S_;
        #pragma unroll
        for (int i = 0; i < 16; ++i)
            rel[i] = *reinterpret_cast<const int4*>(&relrow[hl * 4 + i * 32]);
    }
    auto hist = [&](int c) {
        #pragma unroll
        for (int i = 0; i < 4; ++i) {
            const int4 rv = rel[c * 4 + i];
            atomicAdd(&cnt_s[hrow * NR_ + rv.x], 1);
            atomicAdd(&cnt_s[hrow * NR_ + rv.y], 1);
            atomicAdd(&cnt_s[hrow * NR_ + rv.z], 1);
            atomicAdd(&cnt_s[hrow * NR_ + rv.w], 1);
        }
    };
    for (int g = t; g < NR_ * D_ / 4; g += 256) {       // 264 float4
        const int r = g >> 3, d4 = (g & 7) * 4;
        const float4 ev = *reinterpret_cast<const float4*>(
            &rel_emb[(size_t)r * E_ + c0 + d4]);
        *reinterpret_cast<float4*>(&emb_s[r * D_ + d4]) = ev;
        *reinterpret_cast<uint2*>(&ebf_s[r * 32 + d4]) =
            make_uint2(pk_bf16(ev.x, ev.y), pk_bf16(ev.z, ev.w));
    }
    if (t < 240) reinterpret_cast<unsigned*>(ebf_s + 33 * 32)[t] = 0;  // zero pad rows
    for (int i = t; i < RC_ * NR_; i += 256) cnt_s[i] = 0;

    wtiles(0, 0);                          // tile0 -> buf0 (frees slot 0)
    issue(2, 0);
    bar_lgkm();                            // B1: tile0 visible, cnt zeroed

    // ---- dbuf GEMM loop: one barrier per k-tile ----------------------------
    wtiles(1, 1);  issue(3, 1);            // tile1 -> buf1
    mfma_tile(0);  hist(0);
    bar_lgkm();

    wtiles(0, 0);                          // tile2 -> buf0
    mfma_tile(1);  hist(1);
    bar_lgkm();

    wtiles(1, 1);                          // tile3 -> buf1
    mfma_tile(0);  hist(2);
    bar_lgkm();

    mfma_tile(1);  hist(3);

    // ---- write projections (C: col=lane&15, row=(lane>>4)*4+j) -------------
    #pragma unroll
    for (int j = 0; j < 4; ++j) {
        const int row = mi + (l >> 4) * 4 + j;
        const int col = ni + lr;
        v_s[row][col] = accv[j];
        qbf_s[row * 32 + col] = bf16_1(accq[j]);
    }
    bar_lgkm();                            // B2

    // ---- qr[row][r] = q_row . emb_r via MFMA (32x48, K=32) -----------------
    {
        const int kq = (l >> 4) * 8;
        const int Hh = w >> 1;
        const int G  = w & 1;
        const s16x8 afr = *reinterpret_cast<const s16x8*>(&qbf_s[(Hh * 16 + lr) * 32 + kq]);
        const s16x8 bfr = *reinterpret_cast<const s16x8*>(&ebf_s[(G  * 16 + lr) * 32 + kq]);
        f32x4 r1 = {};
        r1 = __builtin_amdgcn_mfma_f32_16x16x32_bf16(afr, bfr, r1, 0, 0, 0);
        #pragma unroll
        for (int j = 0; j < 4; ++j)
            qr_s[Hh * 16 + (l >> 4) * 4 + j][G * 16 + lr] = r1[j];
        if ((w & 1) == 0) {                // waves 0,2 also do buckets 32-47
            const s16x8 bf2 = *reinterpret_cast<const s16x8*>(&ebf_s[(32 + lr) * 32 + kq]);
            f32x4 r2 = {};
            r2 = __builtin_amdgcn_mfma_f32_16x16x32_bf16(afr, bf2, r2, 0, 0, 0);
            #pragma unroll
            for (int j = 0; j < 4; ++j)
                qr_s[Hh * 16 + (l >> 4) * 4 + j][32 + lr] = r2[j];
        }
    }
    bar_lgkm();                            // B3

    // ---- bucket softmax (8 lanes/row) + output, weights via shfl -----------
    const int erow = hrow, el = hl;
    float e[5];
    float inv;
    {
        constexpr float scale = 0.17677669529663687f;   // 1/sqrt(32)
        float z[5], m = -1e30f;
        #pragma unroll
        for (int u = 0; u < 5; ++u) {
            const int r = el + 8 * u;
            z[u] = (r < NR_) ? qr_s[erow][r] * scale : -1e30f;
            m = fmaxf(m, z[u]);
        }
        m = fmaxf(m, __shfl_xor(m, 1));
        m = fmaxf(m, __shfl_xor(m, 2));
        m = fmaxf(m, __shfl_xor(m, 4));
        float sum = 0.f;
        #pragma unroll
        for (int u = 0; u < 5; ++u) {
            const int r = el + 8 * u;
            e[u] = (r < NR_) ? (float)cnt_s[erow * NR_ + r] * __expf(z[u] - m) : 0.f;
            sum += e[u];
        }
        sum += __shfl_xor(sum, 1);
        sum += __shfl_xor(sum, 2);
        sum += __shfl_xor(sum, 4);
        inv = 1.0f / sum;
    }
    {
        const int d0 = el * 4;
        f32x4 acc = *reinterpret_cast<const f32x4*>(&v_s[erow][d0]);
        const int base = l & 56;                        // 8-lane group base
        #pragma unroll
        for (int r = 0; r < NR_; ++r) {
            const float wv = __shfl(e[r >> 3], base | (r & 7)) * inv;
            const f32x4 ev = *reinterpret_cast<const f32x4*>(&emb_s[r * D_ + d0]);
            acc[0] += wv * ev[0]; acc[1] += wv * ev[1];
            acc[2] += wv * ev[2]; acc[3] += wv * ev[3];
        }
        *reinterpret_cast<f32x4*>(&out[(size_t)(r0 + erow) * E_ + c0 + d0]) = acc;
    }
}

extern "C" void kernel_launch(void* const* d_in, const int* in_sizes, int n_in,
                              void* d_out, int out_size, void* d_ws, size_t ws_size,
                              hipStream_t stream) {
    const float* query     = (const float*)d_in[0];
    const float* value     = (const float*)d_in[2];
    const int*   relations = (const int*)  d_in[3];
    const float* W_Q       = (const float*)d_in[4];
    const float* W_V       = (const float*)d_in[6];
    const float* rel_emb   = (const float*)d_in[7];
    float* out = (float*)d_out;

    dim3 grid(ROWS_ / RC_, H_);            // (32, 8) = 256 blocks, one per CU
    fused_kernel<<<grid, 256, 0, stream>>>(query, value, W_Q, W_V,
                                           relations, rel_emb, out);
}